// Round 2
// baseline (562.720 us; speedup 1.0000x reference)
//
#include <hip/hip_runtime.h>
#include <hip/hip_fp16.h>

// Problem constants: B=1, L=2048, C=2048, H=16, D=128, keys = 2L = 4096
#define LQ 2048
#define CDIM 2048
#define NHEAD 16
#define HDIM 128
#define LKEY 4096

typedef _Float16 f16x8 __attribute__((ext_vector_type(8)));
typedef float f32x4 __attribute__((ext_vector_type(4)));

#define GLOAD_LDS16(g, s) __builtin_amdgcn_global_load_lds( \
    (const __attribute__((address_space(1))) void*)(g),     \
    (__attribute__((address_space(3))) void*)(s), 16, 0, 0)

#define MFMA16(a, b, c) __builtin_amdgcn_mfma_f32_16x16x32_f16(a, b, c, 0, 0, 0)

__device__ __forceinline__ void storeC(float* p, float v) { *p = v; }
__device__ __forceinline__ void storeC(__half* p, float v) { *p = __float2half(v); }
__device__ __forceinline__ float toF(float v) { return v; }
__device__ __forceinline__ float toF(__half v) { return __half2float(v); }

// ---------------------------------------------------------------------------
// C[128bm:+128, 128bn:+128] = A[*,0:K] * B[*,0:K]^T  (fp16 in, fp32 acc)
// 128x128 tile, BK=64, 4 waves, 4x4 acc/wave, global_load_lds staging.
// ---------------------------------------------------------------------------
template <typename OutT>
__global__ __launch_bounds__(256, 2) void gemm_bt(
    const __half* __restrict__ A, const __half* __restrict__ B,
    OutT* __restrict__ C, int lda, int ldb, int ldc, int K)
{
    __shared__ __align__(16) __half lA[128 * 64];
    __shared__ __align__(16) __half lB[128 * 64];
    const int tid  = threadIdx.x;
    const int lane = tid & 63;
    const int wave = tid >> 6;
    const int bm = blockIdx.x, bn = blockIdx.y;
    const int r = tid >> 3;     // 0..31: row within 32-row staging slab
    const int g = tid & 7;      // 8-elem col group
    const __half* gA = A + (long)(bm * 128 + r) * lda + ((g ^ (r & 7)) << 3);
    const __half* gB = B + (long)(bn * 128 + r) * ldb + ((g ^ (r & 7)) << 3);
    __half* lAp = lA + tid * 8;
    __half* lBp = lB + tid * 8;
    const int wr = (wave & 1) << 6;
    const int wc = (wave >> 1) << 6;
    const int l15 = lane & 15, quad = lane >> 4;

    f32x4 acc[4][4] = {};

    for (int kt = 0; kt < K; kt += 64) {
#pragma unroll
        for (int i = 0; i < 4; ++i) {
            GLOAD_LDS16(gA + (long)i * 32 * lda, lAp + i * 2048);
            GLOAD_LDS16(gB + (long)i * 32 * ldb, lBp + i * 2048);
        }
        gA += 64; gB += 64;
        __syncthreads();
#pragma unroll
        for (int kk = 0; kk < 2; ++kk) {
            f16x8 af[4], bfr[4];
#pragma unroll
            for (int mi = 0; mi < 4; ++mi) {
                const int m = wr + mi * 16 + l15;
                const int kg = kk * 4 + quad;
                af[mi] = *(const f16x8*)&lA[m * 64 + ((kg ^ (m & 7)) << 3)];
            }
#pragma unroll
            for (int ni = 0; ni < 4; ++ni) {
                const int n = wc + ni * 16 + l15;
                const int kg = kk * 4 + quad;
                bfr[ni] = *(const f16x8*)&lB[n * 64 + ((kg ^ (n & 7)) << 3)];
            }
#pragma unroll
            for (int mi = 0; mi < 4; ++mi)
#pragma unroll
                for (int ni = 0; ni < 4; ++ni)
                    acc[mi][ni] = MFMA16(af[mi], bfr[ni], acc[mi][ni]);
        }
        __syncthreads();
    }
    const int row0 = bm * 128 + wr + quad * 4;
    const int col0 = bn * 128 + wc + l15;
#pragma unroll
    for (int mi = 0; mi < 4; ++mi)
#pragma unroll
        for (int ni = 0; ni < 4; ++ni)
#pragma unroll
            for (int rx = 0; rx < 4; ++rx)
                storeC(&C[(long)(row0 + mi * 16 + rx) * ldc + col0 + ni * 16],
                       acc[mi][ni][rx]);
}

// ---------------------------------------------------------------------------
// Fused attention tile kernel (max-free softmax, log2-domain scores).
// v3: 256 q-rows/block (mt=4 per wave, 64 rows/wave), grid 8x32 = 256 blocks
// = 1 block/CU. Same 32KB/step K/V staging now feeds 128 MFMA/wave-step
// (K-frags shared across mt; V hoisted to 16 f16x8 regs, reused across mt).
// P slab per-wave (16x76, stride proven conflict-free), reused per mt.
// XCD-affinity swizzle keeps each (h,kc) K/V chunk resident in one L2.
// ---------------------------------------------------------------------------
__global__ __launch_bounds__(256, 1) void attn_tile(
    const __half* __restrict__ Qf,  // [2048][2048] normed+roped, log2-scaled
    const __half* __restrict__ Kf,  // kvf [4096][4096]; K in cols 0..2047
    const __half* __restrict__ Vt,  // [2048][4096]  Vt[h*128+d][key]
    float* __restrict__ Opart,      // [2][2048][2048]
    float* __restrict__ lsum)       // [16][2048]
{
    __shared__ __align__(16) __half lK[64 * 128];    // 16 KB
    __shared__ __align__(16) __half lV[128 * 64];    // 16 KB
    __shared__ __align__(16) __half pL[4 * 16 * 76]; // 9.5 KB per-wave P slabs

    const int tid  = threadIdx.x;
    const int lane = tid & 63;
    const int wave = tid >> 6;
    const int l15  = lane & 15;
    const int quad = lane >> 4;
    // XCD-affinity remap (bijective on 256 blocks): blocks with equal hkc
    // have lin = const (mod 32) -> const (mod 8) -> same XCD.
    const int lin = blockIdx.y * 8 + blockIdx.x;
    const int hkc = (lin & 7) * 4 + ((lin >> 3) & 3);
    const int qt  = lin >> 5;                // 0..7
    const int h   = hkc >> 1;
    const int kc  = hkc & 1;
    const int q0  = qt * 256 + wave * 64;    // this wave's 64 q-rows

    // Q A-fragments: A[m=l15][k=ks*32+quad*8+j], 4 mt sub-tiles of 16 rows
    f16x8 aq[4][4];
#pragma unroll
    for (int mt = 0; mt < 4; ++mt)
#pragma unroll
        for (int ks = 0; ks < 4; ++ks)
            aq[mt][ks] = *(const f16x8*)&Qf[(long)(q0 + mt * 16 + l15) * CDIM +
                                            h * HDIM + ks * 32 + quad * 8];

    // staging pointers. LDS[r][g] = global[r][g ^ (r & mask)] (XOR swizzle in
    // the SOURCE address; LDS dest is wave-uniform base + lane*16).
    const int rK = tid >> 4;          // K row 0..15 (+16/issue)
    const int gK = tid & 15;          // 16 groups of 8 halves
    const __half* srcK = Kf + (long)(kc * 2048 + rK) * 4096 + h * HDIM +
                         ((gK ^ (rK & 15)) << 3);
    const int rV = tid >> 3;          // V row (d) 0..31 (+32/issue)
    const int gV = tid & 7;           // 8 groups of 8 halves
    const __half* srcV = Vt + (long)(h * HDIM + rV) * (long)LKEY + kc * 2048 +
                         ((gV ^ (rV & 7)) << 3);
    __half* dstK = lK + tid * 8;
    __half* dstV = lV + tid * 8;
    __half* pW = pL + wave * (16 * 76);   // per-wave P slab, stride 76 halves

    f32x4 accO[4][8] = {};
    f32x4 l_acc[4] = {};

    for (int st = 0; st < 32; ++st) {
#pragma unroll
        for (int i = 0; i < 4; ++i) {
            GLOAD_LDS16(srcK + (long)(st * 64 + i * 16) * 4096, dstK + i * 2048);
            GLOAD_LDS16(srcV + (long)i * 32 * LKEY + st * 64, dstV + i * 2048);
        }
        __syncthreads();
        // ---- QK^T (acc init -10 folds the exp2 bias); K-frags shared over mt
        f32x4 s[4][4];
#pragma unroll
        for (int mt = 0; mt < 4; ++mt)
#pragma unroll
            for (int nt = 0; nt < 4; ++nt)
                s[mt][nt] = (f32x4){-10.f, -10.f, -10.f, -10.f};
#pragma unroll
        for (int nt = 0; nt < 4; ++nt) {
            const int n = nt * 16 + l15;
#pragma unroll
            for (int ks = 0; ks < 4; ++ks) {
                const f16x8 kf = *(const f16x8*)
                    &lK[n * 128 + (((ks * 4 + quad) ^ (n & 15)) << 3)];
#pragma unroll
                for (int mt = 0; mt < 4; ++mt)
                    s[mt][nt] = MFMA16(aq[mt][ks], kf, s[mt][nt]);
            }
        }
        // ---- hoist V tile into registers (reused across all 4 mt) ----
        f16x8 vr[16];
#pragma unroll
        for (int nt2 = 0; nt2 < 8; ++nt2) {
            const int n2 = nt2 * 16 + l15;
            vr[2 * nt2]     = *(const f16x8*)&lV[n2 * 64 + ((quad ^ (n2 & 7)) << 3)];
            vr[2 * nt2 + 1] = *(const f16x8*)&lV[n2 * 64 + (((4 + quad) ^ (n2 & 7)) << 3)];
        }
        // ---- per mt: P = exp2(s), stage P (per-wave slab), PV ----
#pragma unroll
        for (int mt = 0; mt < 4; ++mt) {
#pragma unroll
            for (int nt = 0; nt < 4; ++nt)
#pragma unroll
                for (int r2 = 0; r2 < 4; ++r2) {
                    const float p = __builtin_amdgcn_exp2f(s[mt][nt][r2]);
                    l_acc[mt][r2] += p;
                    pW[(quad * 4 + r2) * 76 + nt * 16 + l15] = __float2half(p);
                }
            const f16x8 ap0 = *(const f16x8*)&pW[l15 * 76 + quad * 8];
            const f16x8 ap1 = *(const f16x8*)&pW[l15 * 76 + 32 + quad * 8];
#pragma unroll
            for (int nt2 = 0; nt2 < 8; ++nt2) {
                accO[mt][nt2] = MFMA16(ap0, vr[2 * nt2],     accO[mt][nt2]);
                accO[mt][nt2] = MFMA16(ap1, vr[2 * nt2 + 1], accO[mt][nt2]);
            }
        }
        __syncthreads();
    }

    // ---- l: reduce across the 16 l15 lanes, publish via atomics ----
#pragma unroll
    for (int mt = 0; mt < 4; ++mt)
#pragma unroll
        for (int r2 = 0; r2 < 4; ++r2) {
            float v = l_acc[mt][r2];
            v += __shfl_xor(v, 1);
            v += __shfl_xor(v, 2);
            v += __shfl_xor(v, 4);
            v += __shfl_xor(v, 8);
            if (l15 == 0)
                atomicAdd(&lsum[h * LQ + q0 + mt * 16 + quad * 4 + r2], v);
        }
    // ---- O partial (fp32) ----
    float* Cp = Opart + (long)kc * LQ * CDIM + h * HDIM;
#pragma unroll
    for (int mt = 0; mt < 4; ++mt)
#pragma unroll
        for (int nt2 = 0; nt2 < 8; ++nt2)
#pragma unroll
            for (int rx = 0; rx < 4; ++rx)
                Cp[(long)(q0 + mt * 16 + quad * 4 + rx) * CDIM + nt2 * 16 + l15] =
                    accO[mt][nt2][rx];
}

// ---------------------------------------------------------------------------
// merge: a2[q][c] = (Op0+Op1)[q][c] / lsum[c>>7][q]   (fp16 out)
// ---------------------------------------------------------------------------
__global__ __launch_bounds__(256) void merge_o(
    const float* __restrict__ Op, const float* __restrict__ lsum,
    __half* __restrict__ a2)
{
    const int row = blockIdx.x;
    const int c0  = threadIdx.x * 8;
    const float inv = 1.0f / lsum[(c0 >> 7) * LQ + row];
    const float* p0 = Op + (long)row * CDIM + c0;
    const float* p1 = p0 + (long)LQ * CDIM;
    union { f16x8 v; _Float16 e[8]; } o;
#pragma unroll
    for (int j = 0; j < 8; ++j)
        o.e[j] = (_Float16)((p0[j] + p1[j]) * inv);
    *(f16x8*)&a2[(long)row * 4096 + c0] = o.v;
}

// ---------------------------------------------------------------------------
// In-place per-(row,head) rmsnorm + depth-rope on fp16 data (D=128).
// ---------------------------------------------------------------------------
__global__ __launch_bounds__(256) void norm_rope(
    __half* __restrict__ X, const float* __restrict__ w,
    int stride, int nrows, int kmode, float oscale)
{
    const int gid  = blockIdx.x * 4 + (threadIdx.x >> 6);
    const int lane = threadIdx.x & 63;
    const int row  = gid >> 4;
    const int h    = gid & 15;
    if (row >= nrows) return;
    __half* p = X + (long)row * stride + h * HDIM;
    float x1 = __half2float(p[lane]);
    float x2 = __half2float(p[lane + 64]);
    float ss = x1 * x1 + x2 * x2;
#pragma unroll
    for (int off = 1; off < 64; off <<= 1) ss += __shfl_xor(ss, off);
    const float rn = rsqrtf(ss * (1.0f / 128.0f) + 1e-6f);
    x1 *= rn * w[lane];
    x2 *= rn * w[lane + 64];
    const int depth = kmode ? (row < LQ ? 0 : 1) : 2;
    const float freq = exp2f(-(float)lane * 0.20762050593045702f);
    const float ang = (float)depth * freq;
    float sn, cs;
    __sincosf(ang, &sn, &cs);
    p[lane]      = __float2half((x1 * cs - x2 * sn) * oscale);
    p[lane + 64] = __float2half((x1 * sn + x2 * cs) * oscale);
}

// ---------------------------------------------------------------------------
// helpers
// ---------------------------------------------------------------------------
__global__ void cast_h4(const float* __restrict__ in, __half* __restrict__ out, int n) {
    const int i = (blockIdx.x * 256 + threadIdx.x) << 2;
    if (i >= n) return;
    const float4 v = *(const float4*)&in[i];
    out[i]     = __float2half(v.x);
    out[i + 1] = __float2half(v.y);
    out[i + 2] = __float2half(v.z);
    out[i + 3] = __float2half(v.w);
}

__global__ void cast_wo(const float* __restrict__ in, __half* __restrict__ out) {
    const int idx = blockIdx.x * 256 + threadIdx.x;
    const int o = idx >> 11, c = idx & 2047;
    out[((long)o << 12) + c] = __float2half(in[idx]);
}

template <typename InT>
__global__ __launch_bounds__(256) void transpose_h(
    const InT* __restrict__ in, long inStride, long inOff,
    __half* __restrict__ out, long outStride, long outOff)
{
    __shared__ float t[64][65];
    const long r0 = (long)blockIdx.x * 64;
    const long c0 = (long)blockIdx.y * 64;
    const int tj = threadIdx.x & 63;
    const int ti = threadIdx.x >> 6;
#pragma unroll
    for (int it = 0; it < 16; ++it) {
        const int i = it * 4 + ti;
        t[i][tj] = toF(in[(r0 + i) * inStride + inOff + c0 + tj]);
    }
    __syncthreads();
#pragma unroll
    for (int it = 0; it < 16; ++it) {
        const int i = it * 4 + ti;
        out[(c0 + i) * outStride + outOff + r0 + tj] = __float2half(t[tj][i]);
    }
}

__global__ void sin_feat(const float* __restrict__ sw1, const float* __restrict__ sb1,
                         __half* __restrict__ a2) {
    const int idx = blockIdx.x * 256 + threadIdx.x;
    const int l = idx >> 11, c = idx & 2047;
    const float coord = -1.0f + (2.0f / 2047.0f) * (float)l;
    const float v = sinf(30.0f * (coord * sw1[c] + sb1[c]));
    a2[((long)l << 12) + 2048 + c] = __float2half(v);
}

__global__ __launch_bounds__(256) void final_norm(
    const float* __restrict__ out2, const float* __restrict__ x,
    const float* __restrict__ sb2, const float* __restrict__ on_w,
    float* __restrict__ y)
{
    const int row = blockIdx.x;
    const float* o = out2 + (long)row * CDIM;
    float v[8];
    float ss = 0.f;
#pragma unroll
    for (int i = 0; i < 8; ++i) {
        const int c = threadIdx.x + i * 256;
        const float t = o[c] + sb2[c];
        v[i] = t;
        ss += t * t;
    }
#pragma unroll
    for (int off = 1; off < 64; off <<= 1) ss += __shfl_xor(ss, off);
    __shared__ float red[4];
    const int lane = threadIdx.x & 63, wv = threadIdx.x >> 6;
    if (lane == 0) red[wv] = ss;
    __syncthreads();
    const float tot = red[0] + red[1] + red[2] + red[3];
    const float rn = rsqrtf(tot * (1.0f / 2048.0f) + 1e-6f);
#pragma unroll
    for (int i = 0; i < 8; ++i) {
        const int c = threadIdx.x + i * 256;
        y[(long)row * CDIM + c] = x[(long)row * CDIM + c] + v[i] * rn * on_w[c];
    }
}

// ---------------------------------------------------------------------------
extern "C" void kernel_launch(void* const* d_in, const int* in_sizes, int n_in,
                              void* d_out, int out_size, void* d_ws, size_t ws_size,
                              hipStream_t stream) {
    const float* x    = (const float*)d_in[0];
    const float* h0   = (const float*)d_in[1];
    const float* h1   = (const float*)d_in[2];
    const float* h2   = (const float*)d_in[3];
    const float* Wq   = (const float*)d_in[4];
    const float* Wk   = (const float*)d_in[5];
    const float* Wv   = (const float*)d_in[6];
    const float* Wo   = (const float*)d_in[7];
    const float* qn_w = (const float*)d_in[8];
    const float* kn_w = (const float*)d_in[9];
    const float* on_w = (const float*)d_in[10];
    const float* sw1  = (const float*)d_in[11];
    const float* sb1  = (const float*)d_in[12];
    const float* sw2  = (const float*)d_in[13];
    const float* sb2  = (const float*)d_in[14];
    float* y = (float*)d_out;

    const size_t MB = 1ull << 20;
    char* w = (char*)d_ws;
    __half* xq  = (__half*)(w);             //  8 MB  h2 fp16        (dead after Q gemm)
    __half* xkv = (__half*)(w + 8 * MB);    // 16 MB  [h0;h1] fp16   (dead after KV gemm)
    __half* wqh = (__half*)(w + 24 * MB);   //  8 MB  Wq fp16        (dead after Q gemm)
    __half* wkv = (__half*)(w + 32 * MB);   // 16 MB  [Wk;Wv] fp16   (dead after KV gemm)
    __half* qf  = (__half*)(w + 48 * MB);   //  8 MB  Q proj -> normed q
    __half* kvf = (__half*)(w + 56 * MB);   // 32 MB  [K|V] proj (4096x4096)
    __half* vT  = (__half*)(w + 88 * MB);   // 16 MB  V transposed (2048x4096)
    __half* a2  = (__half*)(w + 104 * MB);  // 16 MB  [attn_out | sin_feat]
    __half* b2  = (__half*)(w + 120 * MB);  // 16 MB  [Wo | sw2^T]
    float* out2 = (float*)(w + 136 * MB);   // 16 MB  final GEMM out
    float* Opart = (float*)(w);             // 32 MB  overlays xq/xkv/wqh (dead)
    float* lsum  = (float*)(w + 32 * MB);   // 128 KB overlays wkv (dead)
    (void)in_sizes; (void)n_in; (void)out_size; (void)ws_size;

    const int n4 = 2048 * 2048;
    cast_h4<<<n4 / 1024, 256, 0, stream>>>(h2, xq, n4);
    cast_h4<<<n4 / 1024, 256, 0, stream>>>(h0, xkv, n4);
    cast_h4<<<n4 / 1024, 256, 0, stream>>>(h1, xkv + n4, n4);
    cast_h4<<<n4 / 1024, 256, 0, stream>>>(Wq, wqh, n4);
    cast_h4<<<n4 / 1024, 256, 0, stream>>>(Wk, wkv, n4);
    cast_h4<<<n4 / 1024, 256, 0, stream>>>(Wv, wkv + n4, n4);
    cast_wo<<<n4 / 256, 256, 0, stream>>>(Wo, b2);
    transpose_h<float><<<dim3(32, 32), 256, 0, stream>>>(sw2, 2048, 0, b2, 4096, 2048);
    sin_feat<<<n4 / 256, 256, 0, stream>>>(sw1, sb1, a2);

    gemm_bt<__half><<<dim3(16, 16), 256, 0, stream>>>(xq, wqh, qf, 2048, 2048, 2048, 2048);
    gemm_bt<__half><<<dim3(32, 32), 256, 0, stream>>>(xkv, wkv, kvf, 2048, 2048, 4096, 2048);

    // q pre-scale = log2(e)/sqrt(D): scores arrive in log2 domain for exp2
    norm_rope<<<8192, 256, 0, stream>>>(qf, qn_w, 2048, 2048, 0, 0.12751743f);
    norm_rope<<<16384, 256, 0, stream>>>(kvf, kn_w, 4096, 4096, 1, 1.0f);
    transpose_h<__half><<<dim3(64, 32), 256, 0, stream>>>(kvf, 4096, 2048, vT, 4096, 0);

    (void)hipMemsetAsync(lsum, 0, NHEAD * LQ * sizeof(float), stream);
    attn_tile<<<dim3(8, 32), 256, 0, stream>>>(qf, kvf, vT, Opart, lsum);
    merge_o<<<2048, 256, 0, stream>>>(Opart, lsum, a2);

    gemm_bt<float><<<dim3(16, 16), 256, 0, stream>>>(a2, b2, out2, 4096, 4096, 2048, 4096);
    final_norm<<<2048, 256, 0, stream>>>(out2, x, sb2, on_w, y);
}

// Round 3
// 539.597 us; speedup vs baseline: 1.0429x; 1.0429x over previous
//
#include <hip/hip_runtime.h>
#include <hip/hip_fp16.h>

// Problem constants: B=1, L=2048, C=2048, H=16, D=128, keys = 2L = 4096
#define LQ 2048
#define CDIM 2048
#define NHEAD 16
#define HDIM 128
#define LKEY 4096

typedef _Float16 f16x8 __attribute__((ext_vector_type(8)));
typedef float f32x4 __attribute__((ext_vector_type(4)));

#define GLOAD_LDS16(g, s) __builtin_amdgcn_global_load_lds( \
    (const __attribute__((address_space(1))) void*)(g),     \
    (__attribute__((address_space(3))) void*)(s), 16, 0, 0)

#define MFMA16(a, b, c) __builtin_amdgcn_mfma_f32_16x16x32_f16(a, b, c, 0, 0, 0)

__device__ __forceinline__ void storeC(float* p, float v) { *p = v; }
__device__ __forceinline__ void storeC(__half* p, float v) { *p = __float2half(v); }
__device__ __forceinline__ float toF(float v) { return v; }
__device__ __forceinline__ float toF(__half v) { return __half2float(v); }

// ---------------------------------------------------------------------------
// C[128bm:+128, 128bn:+128] = A[*,0:K] * B[*,0:K]^T  (fp16 in, fp32 acc)
// 128x128 tile, BK=64, 4 waves, 4x4 acc/wave, global_load_lds staging.
// ---------------------------------------------------------------------------
template <typename OutT>
__global__ __launch_bounds__(256, 2) void gemm_bt(
    const __half* __restrict__ A, const __half* __restrict__ B,
    OutT* __restrict__ C, int lda, int ldb, int ldc, int K)
{
    __shared__ __align__(16) __half lA[128 * 64];
    __shared__ __align__(16) __half lB[128 * 64];
    const int tid  = threadIdx.x;
    const int lane = tid & 63;
    const int wave = tid >> 6;
    const int bm = blockIdx.x, bn = blockIdx.y;
    const int r = tid >> 3;     // 0..31: row within 32-row staging slab
    const int g = tid & 7;      // 8-elem col group
    const __half* gA = A + (long)(bm * 128 + r) * lda + ((g ^ (r & 7)) << 3);
    const __half* gB = B + (long)(bn * 128 + r) * ldb + ((g ^ (r & 7)) << 3);
    __half* lAp = lA + tid * 8;
    __half* lBp = lB + tid * 8;
    const int wr = (wave & 1) << 6;
    const int wc = (wave >> 1) << 6;
    const int l15 = lane & 15, quad = lane >> 4;

    f32x4 acc[4][4] = {};

    for (int kt = 0; kt < K; kt += 64) {
#pragma unroll
        for (int i = 0; i < 4; ++i) {
            GLOAD_LDS16(gA + (long)i * 32 * lda, lAp + i * 2048);
            GLOAD_LDS16(gB + (long)i * 32 * ldb, lBp + i * 2048);
        }
        gA += 64; gB += 64;
        __syncthreads();
#pragma unroll
        for (int kk = 0; kk < 2; ++kk) {
            f16x8 af[4], bfr[4];
#pragma unroll
            for (int mi = 0; mi < 4; ++mi) {
                const int m = wr + mi * 16 + l15;
                const int kg = kk * 4 + quad;
                af[mi] = *(const f16x8*)&lA[m * 64 + ((kg ^ (m & 7)) << 3)];
            }
#pragma unroll
            for (int ni = 0; ni < 4; ++ni) {
                const int n = wc + ni * 16 + l15;
                const int kg = kk * 4 + quad;
                bfr[ni] = *(const f16x8*)&lB[n * 64 + ((kg ^ (n & 7)) << 3)];
            }
#pragma unroll
            for (int mi = 0; mi < 4; ++mi)
#pragma unroll
                for (int ni = 0; ni < 4; ++ni)
                    acc[mi][ni] = MFMA16(af[mi], bfr[ni], acc[mi][ni]);
        }
        __syncthreads();
    }
    const int row0 = bm * 128 + wr + quad * 4;
    const int col0 = bn * 128 + wc + l15;
#pragma unroll
    for (int mi = 0; mi < 4; ++mi)
#pragma unroll
        for (int ni = 0; ni < 4; ++ni)
#pragma unroll
            for (int rx = 0; rx < 4; ++rx)
                storeC(&C[(long)(row0 + mi * 16 + rx) * ldc + col0 + ni * 16],
                       acc[mi][ni][rx]);
}

// ---------------------------------------------------------------------------
// Fused attention tile kernel (max-free softmax, log2-domain scores).
// v4: v1 shape (128 q-rows/block, 32/wave, grid 16x32 = 512 blocks = 2/CU)
// + double-buffered K/V with early STAGE issue: next tile's global_load_lds
// issued at step top, single __syncthreads at step end (its vmcnt(0) drain
// lands after the compute, hiding staging latency). Per-wave P slab stride
// 76 (conflict-free, v2/v3-proven), reused sequentially across mt; V tile
// hoisted to 16 regs per step. XCD-affinity swizzle keeps each (h,kc) K/V
// chunk in one XCD's L2.
// ---------------------------------------------------------------------------
__global__ __launch_bounds__(256, 2) void attn_tile(
    const __half* __restrict__ Qf,  // [2048][2048] normed+roped, log2-scaled
    const __half* __restrict__ Kf,  // kvf [4096][4096]; K in cols 0..2047
    const __half* __restrict__ Vt,  // [2048][4096]  Vt[h*128+d][key]
    float* __restrict__ Opart,      // [2][2048][2048]
    float* __restrict__ lsum)       // [16][2048]
{
    __shared__ __align__(16) __half lK[2][64 * 128];   // 32 KB (dbuf)
    __shared__ __align__(16) __half lV[2][128 * 64];   // 32 KB (dbuf)
    __shared__ __align__(16) __half pL[4 * 16 * 76];   // 9.5 KB per-wave P

    const int tid  = threadIdx.x;
    const int lane = tid & 63;
    const int wave = tid >> 6;
    const int l15  = lane & 15;
    const int quad = lane >> 4;
    // XCD-affinity remap (bijective on 512 blocks): blocks with equal hkc
    // have lin = const (mod 8) -> same XCD (round-robin dispatch).
    const int lin = blockIdx.y * 16 + blockIdx.x;
    const int hkc = (lin & 7) * 4 + ((lin >> 3) & 3);
    const int qt  = lin >> 5;                // 0..15
    const int h   = hkc >> 1;
    const int kc  = hkc & 1;
    const int q0  = qt * 128 + wave * 32;    // this wave's 32 q-rows

    // Q A-fragments: A[m=l15][k=ks*32+quad*8+j]
    f16x8 aq[2][4];
#pragma unroll
    for (int mt = 0; mt < 2; ++mt)
#pragma unroll
        for (int ks = 0; ks < 4; ++ks)
            aq[mt][ks] = *(const f16x8*)&Qf[(long)(q0 + mt * 16 + l15) * CDIM +
                                            h * HDIM + ks * 32 + quad * 8];

    // staging pointers. LDS[r][g] = global[r][g ^ (r & mask)] (XOR swizzle in
    // the SOURCE address; LDS dest is wave-uniform base + lane*16).
    const int rK = tid >> 4;          // K row 0..15 (+16/issue)
    const int gK = tid & 15;          // 16 groups of 8 halves
    const __half* srcK = Kf + (long)(kc * 2048 + rK) * 4096 + h * HDIM +
                         ((gK ^ (rK & 15)) << 3);
    const int rV = tid >> 3;          // V row (d) 0..31 (+32/issue)
    const int gV = tid & 7;           // 8 groups of 8 halves
    const __half* srcV = Vt + (long)(h * HDIM + rV) * (long)LKEY + kc * 2048 +
                         ((gV ^ (rV & 7)) << 3);
    __half* pW = pL + wave * (16 * 76);   // per-wave P slab, stride 76 halves

    f32x4 accO[2][8] = {};
    f32x4 l_acc[2] = {};

    // ---- prologue: stage tile 0 into buffer 0 ----
#pragma unroll
    for (int i = 0; i < 4; ++i) {
        GLOAD_LDS16(srcK + (long)(i * 16) * 4096, lK[0] + tid * 8 + i * 2048);
        GLOAD_LDS16(srcV + (long)i * 32 * LKEY, lV[0] + tid * 8 + i * 2048);
    }
    __syncthreads();

    for (int st = 0; st < 32; ++st) {
        const int cur = st & 1;
        // ---- issue next tile's staging early (hidden under compute) ----
        if (st < 31) {
#pragma unroll
            for (int i = 0; i < 4; ++i) {
                GLOAD_LDS16(srcK + (long)((st + 1) * 64 + i * 16) * 4096,
                            lK[cur ^ 1] + tid * 8 + i * 2048);
                GLOAD_LDS16(srcV + (long)i * 32 * LKEY + (st + 1) * 64,
                            lV[cur ^ 1] + tid * 8 + i * 2048);
            }
        }
        const __half* bK = lK[cur];
        const __half* bV = lV[cur];
        // ---- QK^T (acc init -10 folds the exp2 bias) ----
        f32x4 s[2][4];
#pragma unroll
        for (int mt = 0; mt < 2; ++mt)
#pragma unroll
            for (int nt = 0; nt < 4; ++nt)
                s[mt][nt] = (f32x4){-10.f, -10.f, -10.f, -10.f};
#pragma unroll
        for (int nt = 0; nt < 4; ++nt) {
            const int n = nt * 16 + l15;
#pragma unroll
            for (int ks = 0; ks < 4; ++ks) {
                const f16x8 kf = *(const f16x8*)
                    &bK[n * 128 + (((ks * 4 + quad) ^ (n & 15)) << 3)];
                s[0][nt] = MFMA16(aq[0][ks], kf, s[0][nt]);
                s[1][nt] = MFMA16(aq[1][ks], kf, s[1][nt]);
            }
        }
        // ---- hoist V tile into registers (reused across both mt) ----
        f16x8 vr[16];
#pragma unroll
        for (int nt2 = 0; nt2 < 8; ++nt2) {
            const int n2 = nt2 * 16 + l15;
            vr[2 * nt2]     = *(const f16x8*)&bV[n2 * 64 + ((quad ^ (n2 & 7)) << 3)];
            vr[2 * nt2 + 1] = *(const f16x8*)&bV[n2 * 64 + (((4 + quad) ^ (n2 & 7)) << 3)];
        }
        // ---- per mt: P = exp2(s), stage P (per-wave slab), PV ----
#pragma unroll
        for (int mt = 0; mt < 2; ++mt) {
#pragma unroll
            for (int nt = 0; nt < 4; ++nt)
#pragma unroll
                for (int r2 = 0; r2 < 4; ++r2) {
                    const float p = __builtin_amdgcn_exp2f(s[mt][nt][r2]);
                    l_acc[mt][r2] += p;
                    pW[(quad * 4 + r2) * 76 + nt * 16 + l15] = __float2half(p);
                }
            const f16x8 ap0 = *(const f16x8*)&pW[l15 * 76 + quad * 8];
            const f16x8 ap1 = *(const f16x8*)&pW[l15 * 76 + 32 + quad * 8];
#pragma unroll
            for (int nt2 = 0; nt2 < 8; ++nt2) {
                accO[mt][nt2] = MFMA16(ap0, vr[2 * nt2],     accO[mt][nt2]);
                accO[mt][nt2] = MFMA16(ap1, vr[2 * nt2 + 1], accO[mt][nt2]);
            }
        }
        // one barrier/step: drains this wave's staging loads (vmcnt 0) and
        // guarantees all waves are done reading buf[cur] before overwrite.
        __syncthreads();
    }

    // ---- l: reduce across the 16 l15 lanes, publish via atomics ----
#pragma unroll
    for (int mt = 0; mt < 2; ++mt)
#pragma unroll
        for (int r2 = 0; r2 < 4; ++r2) {
            float v = l_acc[mt][r2];
            v += __shfl_xor(v, 1);
            v += __shfl_xor(v, 2);
            v += __shfl_xor(v, 4);
            v += __shfl_xor(v, 8);
            if (l15 == 0)
                atomicAdd(&lsum[h * LQ + q0 + mt * 16 + quad * 4 + r2], v);
        }
    // ---- O partial (fp32) ----
    float* Cp = Opart + (long)kc * LQ * CDIM + h * HDIM;
#pragma unroll
    for (int mt = 0; mt < 2; ++mt)
#pragma unroll
        for (int nt2 = 0; nt2 < 8; ++nt2)
#pragma unroll
            for (int rx = 0; rx < 4; ++rx)
                Cp[(long)(q0 + mt * 16 + quad * 4 + rx) * CDIM + nt2 * 16 + l15] =
                    accO[mt][nt2][rx];
}

// ---------------------------------------------------------------------------
// merge: a2[q][c] = (Op0+Op1)[q][c] / lsum[c>>7][q]   (fp16 out)
// ---------------------------------------------------------------------------
__global__ __launch_bounds__(256) void merge_o(
    const float* __restrict__ Op, const float* __restrict__ lsum,
    __half* __restrict__ a2)
{
    const int row = blockIdx.x;
    const int c0  = threadIdx.x * 8;
    const float inv = 1.0f / lsum[(c0 >> 7) * LQ + row];
    const float* p0 = Op + (long)row * CDIM + c0;
    const float* p1 = p0 + (long)LQ * CDIM;
    union { f16x8 v; _Float16 e[8]; } o;
#pragma unroll
    for (int j = 0; j < 8; ++j)
        o.e[j] = (_Float16)((p0[j] + p1[j]) * inv);
    *(f16x8*)&a2[(long)row * 4096 + c0] = o.v;
}

// ---------------------------------------------------------------------------
// In-place per-(row,head) rmsnorm + depth-rope on fp16 data (D=128).
// ---------------------------------------------------------------------------
__global__ __launch_bounds__(256) void norm_rope(
    __half* __restrict__ X, const float* __restrict__ w,
    int stride, int nrows, int kmode, float oscale)
{
    const int gid  = blockIdx.x * 4 + (threadIdx.x >> 6);
    const int lane = threadIdx.x & 63;
    const int row  = gid >> 4;
    const int h    = gid & 15;
    if (row >= nrows) return;
    __half* p = X + (long)row * stride + h * HDIM;
    float x1 = __half2float(p[lane]);
    float x2 = __half2float(p[lane + 64]);
    float ss = x1 * x1 + x2 * x2;
#pragma unroll
    for (int off = 1; off < 64; off <<= 1) ss += __shfl_xor(ss, off);
    const float rn = rsqrtf(ss * (1.0f / 128.0f) + 1e-6f);
    x1 *= rn * w[lane];
    x2 *= rn * w[lane + 64];
    const int depth = kmode ? (row < LQ ? 0 : 1) : 2;
    const float freq = exp2f(-(float)lane * 0.20762050593045702f);
    const float ang = (float)depth * freq;
    float sn, cs;
    __sincosf(ang, &sn, &cs);
    p[lane]      = __float2half((x1 * cs - x2 * sn) * oscale);
    p[lane + 64] = __float2half((x1 * sn + x2 * cs) * oscale);
}

// ---------------------------------------------------------------------------
// helpers
// ---------------------------------------------------------------------------
__global__ void cast_h4(const float* __restrict__ in, __half* __restrict__ out, int n) {
    const int i = (blockIdx.x * 256 + threadIdx.x) << 2;
    if (i >= n) return;
    const float4 v = *(const float4*)&in[i];
    out[i]     = __float2half(v.x);
    out[i + 1] = __float2half(v.y);
    out[i + 2] = __float2half(v.z);
    out[i + 3] = __float2half(v.w);
}

__global__ void cast_wo(const float* __restrict__ in, __half* __restrict__ out) {
    const int idx = blockIdx.x * 256 + threadIdx.x;
    const int o = idx >> 11, c = idx & 2047;
    out[((long)o << 12) + c] = __float2half(in[idx]);
}

template <typename InT>
__global__ __launch_bounds__(256) void transpose_h(
    const InT* __restrict__ in, long inStride, long inOff,
    __half* __restrict__ out, long outStride, long outOff)
{
    __shared__ float t[64][65];
    const long r0 = (long)blockIdx.x * 64;
    const long c0 = (long)blockIdx.y * 64;
    const int tj = threadIdx.x & 63;
    const int ti = threadIdx.x >> 6;
#pragma unroll
    for (int it = 0; it < 16; ++it) {
        const int i = it * 4 + ti;
        t[i][tj] = toF(in[(r0 + i) * inStride + inOff + c0 + tj]);
    }
    __syncthreads();
#pragma unroll
    for (int it = 0; it < 16; ++it) {
        const int i = it * 4 + ti;
        out[(c0 + i) * outStride + outOff + r0 + tj] = __float2half(t[tj][i]);
    }
}

__global__ void sin_feat(const float* __restrict__ sw1, const float* __restrict__ sb1,
                         __half* __restrict__ a2) {
    const int idx = blockIdx.x * 256 + threadIdx.x;
    const int l = idx >> 11, c = idx & 2047;
    const float coord = -1.0f + (2.0f / 2047.0f) * (float)l;
    const float v = sinf(30.0f * (coord * sw1[c] + sb1[c]));
    a2[((long)l << 12) + 2048 + c] = __float2half(v);
}

__global__ __launch_bounds__(256) void final_norm(
    const float* __restrict__ out2, const float* __restrict__ x,
    const float* __restrict__ sb2, const float* __restrict__ on_w,
    float* __restrict__ y)
{
    const int row = blockIdx.x;
    const float* o = out2 + (long)row * CDIM;
    float v[8];
    float ss = 0.f;
#pragma unroll
    for (int i = 0; i < 8; ++i) {
        const int c = threadIdx.x + i * 256;
        const float t = o[c] + sb2[c];
        v[i] = t;
        ss += t * t;
    }
#pragma unroll
    for (int off = 1; off < 64; off <<= 1) ss += __shfl_xor(ss, off);
    __shared__ float red[4];
    const int lane = threadIdx.x & 63, wv = threadIdx.x >> 6;
    if (lane == 0) red[wv] = ss;
    __syncthreads();
    const float tot = red[0] + red[1] + red[2] + red[3];
    const float rn = rsqrtf(tot * (1.0f / 2048.0f) + 1e-6f);
#pragma unroll
    for (int i = 0; i < 8; ++i) {
        const int c = threadIdx.x + i * 256;
        y[(long)row * CDIM + c] = x[(long)row * CDIM + c] + v[i] * rn * on_w[c];
    }
}

// ---------------------------------------------------------------------------
extern "C" void kernel_launch(void* const* d_in, const int* in_sizes, int n_in,
                              void* d_out, int out_size, void* d_ws, size_t ws_size,
                              hipStream_t stream) {
    const float* x    = (const float*)d_in[0];
    const float* h0   = (const float*)d_in[1];
    const float* h1   = (const float*)d_in[2];
    const float* h2   = (const float*)d_in[3];
    const float* Wq   = (const float*)d_in[4];
    const float* Wk   = (const float*)d_in[5];
    const float* Wv   = (const float*)d_in[6];
    const float* Wo   = (const float*)d_in[7];
    const float* qn_w = (const float*)d_in[8];
    const float* kn_w = (const float*)d_in[9];
    const float* on_w = (const float*)d_in[10];
    const float* sw1  = (const float*)d_in[11];
    const float* sb1  = (const float*)d_in[12];
    const float* sw2  = (const float*)d_in[13];
    const float* sb2  = (const float*)d_in[14];
    float* y = (float*)d_out;

    const size_t MB = 1ull << 20;
    char* w = (char*)d_ws;
    __half* xq  = (__half*)(w);             //  8 MB  h2 fp16        (dead after Q gemm)
    __half* xkv = (__half*)(w + 8 * MB);    // 16 MB  [h0;h1] fp16   (dead after KV gemm)
    __half* wqh = (__half*)(w + 24 * MB);   //  8 MB  Wq fp16        (dead after Q gemm)
    __half* wkv = (__half*)(w + 32 * MB);   // 16 MB  [Wk;Wv] fp16   (dead after KV gemm)
    __half* qf  = (__half*)(w + 48 * MB);   //  8 MB  Q proj -> normed q
    __half* kvf = (__half*)(w + 56 * MB);   // 32 MB  [K|V] proj (4096x4096)
    __half* vT  = (__half*)(w + 88 * MB);   // 16 MB  V transposed (2048x4096)
    __half* a2  = (__half*)(w + 104 * MB);  // 16 MB  [attn_out | sin_feat]
    __half* b2  = (__half*)(w + 120 * MB);  // 16 MB  [Wo | sw2^T]
    float* out2 = (float*)(w + 136 * MB);   // 16 MB  final GEMM out
    float* Opart = (float*)(w);             // 32 MB  overlays xq/xkv/wqh (dead)
    float* lsum  = (float*)(w + 32 * MB);   // 128 KB overlays wkv (dead)
    (void)in_sizes; (void)n_in; (void)out_size; (void)ws_size;

    const int n4 = 2048 * 2048;
    cast_h4<<<n4 / 1024, 256, 0, stream>>>(h2, xq, n4);
    cast_h4<<<n4 / 1024, 256, 0, stream>>>(h0, xkv, n4);
    cast_h4<<<n4 / 1024, 256, 0, stream>>>(h1, xkv + n4, n4);
    cast_h4<<<n4 / 1024, 256, 0, stream>>>(Wq, wqh, n4);
    cast_h4<<<n4 / 1024, 256, 0, stream>>>(Wk, wkv, n4);
    cast_h4<<<n4 / 1024, 256, 0, stream>>>(Wv, wkv + n4, n4);
    cast_wo<<<n4 / 256, 256, 0, stream>>>(Wo, b2);
    transpose_h<float><<<dim3(32, 32), 256, 0, stream>>>(sw2, 2048, 0, b2, 4096, 2048);
    sin_feat<<<n4 / 256, 256, 0, stream>>>(sw1, sb1, a2);

    gemm_bt<__half><<<dim3(16, 16), 256, 0, stream>>>(xq, wqh, qf, 2048, 2048, 2048, 2048);
    gemm_bt<__half><<<dim3(32, 32), 256, 0, stream>>>(xkv, wkv, kvf, 2048, 2048, 4096, 2048);

    // q pre-scale = log2(e)/sqrt(D): scores arrive in log2 domain for exp2
    norm_rope<<<8192, 256, 0, stream>>>(qf, qn_w, 2048, 2048, 0, 0.12751743f);
    norm_rope<<<16384, 256, 0, stream>>>(kvf, kn_w, 4096, 4096, 1, 1.0f);
    transpose_h<__half><<<dim3(64, 32), 256, 0, stream>>>(kvf, 4096, 2048, vT, 4096, 0);

    (void)hipMemsetAsync(lsum, 0, NHEAD * LQ * sizeof(float), stream);
    attn_tile<<<dim3(16, 32), 256, 0, stream>>>(qf, kvf, vT, Opart, lsum);
    merge_o<<<2048, 256, 0, stream>>>(Opart, lsum, a2);

    gemm_bt<float><<<dim3(16, 16), 256, 0, stream>>>(a2, b2, out2, 4096, 4096, 2048, 4096);
    final_norm<<<2048, 256, 0, stream>>>(out2, x, sb2, on_w, y);
}

// Round 4
// 454.060 us; speedup vs baseline: 1.2393x; 1.1884x over previous
//
#include <hip/hip_runtime.h>
#include <hip/hip_fp16.h>

// Problem constants: B=1, L=2048, C=2048, H=16, D=128, keys = 2L = 4096
#define LQ 2048
#define CDIM 2048
#define NHEAD 16
#define HDIM 128
#define LKEY 4096

typedef _Float16 f16x8 __attribute__((ext_vector_type(8)));
typedef _Float16 f16x4 __attribute__((ext_vector_type(4)));
typedef float f32x4 __attribute__((ext_vector_type(4)));

#define GLOAD_LDS16(g, s) __builtin_amdgcn_global_load_lds( \
    (const __attribute__((address_space(1))) void*)(g),     \
    (__attribute__((address_space(3))) void*)(s), 16, 0, 0)

#define MFMA16(a, b, c) __builtin_amdgcn_mfma_f32_16x16x32_f16(a, b, c, 0, 0, 0)

__device__ __forceinline__ void storeC(float* p, float v) { *p = v; }
__device__ __forceinline__ void storeC(__half* p, float v) { *p = __float2half(v); }
__device__ __forceinline__ float toF(float v) { return v; }
__device__ __forceinline__ float toF(__half v) { return __half2float(v); }

// ---------------------------------------------------------------------------
// Shared GEMM body: C[128bmC:+128, 128bn:+128] = A[128bmA:+128, :K] * B^T
// 128x128 tile, BK=64, 4 waves, 4x4 acc/wave, global_load_lds staging.
// ---------------------------------------------------------------------------
template <typename OutT>
__device__ __forceinline__ void gemm_body(
    const __half* __restrict__ A, const __half* __restrict__ B,
    OutT* __restrict__ C, int lda, int ldb, int ldc, int K,
    int bmA, int bmC, int bn)
{
    __shared__ __align__(16) __half lA[128 * 64];
    __shared__ __align__(16) __half lB[128 * 64];
    const int tid  = threadIdx.x;
    const int lane = tid & 63;
    const int wave = tid >> 6;
    const int r = tid >> 3;     // 0..31: row within 32-row staging slab
    const int g = tid & 7;      // 8-elem col group
    const __half* gA = A + (long)(bmA * 128 + r) * lda + ((g ^ (r & 7)) << 3);
    const __half* gB = B + (long)(bn * 128 + r) * ldb + ((g ^ (r & 7)) << 3);
    __half* lAp = lA + tid * 8;
    __half* lBp = lB + tid * 8;
    const int wr = (wave & 1) << 6;
    const int wc = (wave >> 1) << 6;
    const int l15 = lane & 15, quad = lane >> 4;

    f32x4 acc[4][4] = {};

    for (int kt = 0; kt < K; kt += 64) {
#pragma unroll
        for (int i = 0; i < 4; ++i) {
            GLOAD_LDS16(gA + (long)i * 32 * lda, lAp + i * 2048);
            GLOAD_LDS16(gB + (long)i * 32 * ldb, lBp + i * 2048);
        }
        gA += 64; gB += 64;
        __syncthreads();
#pragma unroll
        for (int kk = 0; kk < 2; ++kk) {
            f16x8 af[4], bfr[4];
#pragma unroll
            for (int mi = 0; mi < 4; ++mi) {
                const int m = wr + mi * 16 + l15;
                const int kg = kk * 4 + quad;
                af[mi] = *(const f16x8*)&lA[m * 64 + ((kg ^ (m & 7)) << 3)];
            }
#pragma unroll
            for (int ni = 0; ni < 4; ++ni) {
                const int n = wc + ni * 16 + l15;
                const int kg = kk * 4 + quad;
                bfr[ni] = *(const f16x8*)&lB[n * 64 + ((kg ^ (n & 7)) << 3)];
            }
#pragma unroll
            for (int mi = 0; mi < 4; ++mi)
#pragma unroll
                for (int ni = 0; ni < 4; ++ni)
                    acc[mi][ni] = MFMA16(af[mi], bfr[ni], acc[mi][ni]);
        }
        __syncthreads();
    }
    const int row0 = bmC * 128 + wr + quad * 4;
    const int col0 = bn * 128 + wc + l15;
#pragma unroll
    for (int mi = 0; mi < 4; ++mi)
#pragma unroll
        for (int ni = 0; ni < 4; ++ni)
#pragma unroll
            for (int rx = 0; rx < 4; ++rx)
                storeC(&C[(long)(row0 + mi * 16 + rx) * ldc + col0 + ni * 16],
                       acc[mi][ni][rx]);
}

// ---------------------------------------------------------------------------
// Fused Q+KV projection GEMM, one launch (1280 blocks = good machine fill;
// separate 256-block Q gemm ran at 1 block/CU = latency-exposed).
// A = [xq; xkv] contiguous (6144 x 2048). Blocks 0..1023: KV tiles
// (Ckv 4096x4096); blocks 1024..1279: Q tiles (Cq 2048x2048).
// ---------------------------------------------------------------------------
__global__ __launch_bounds__(256, 2) void gemm_qkv(
    const __half* __restrict__ A, const __half* __restrict__ Bq,
    const __half* __restrict__ Bkv, __half* __restrict__ Cq,
    __half* __restrict__ Ckv)
{
    const int lin = blockIdx.x;
    if (lin < 1024) {
        const int bm = lin & 31, bn = lin >> 5;
        gemm_body<__half>(A, Bkv, Ckv, 2048, 2048, 4096, 2048, bm + 16, bm, bn);
    } else {
        const int l2 = lin - 1024;
        const int bm = l2 & 15, bn = l2 >> 4;
        gemm_body<__half>(A, Bq, Cq, 2048, 2048, 2048, 2048, bm, bm, bn);
    }
}

// ---------------------------------------------------------------------------
// Split-K final GEMM: grid (16,16,2); z selects K-half, partials into
// C + z*LQ*CDIM. (256-block full-K version ran at 1 block/CU.)
// ---------------------------------------------------------------------------
__global__ __launch_bounds__(256, 2) void gemm_sk(
    const __half* __restrict__ A, const __half* __restrict__ B,
    float* __restrict__ C, int lda, int ldb, int ldc, int Khalf)
{
    const int z = blockIdx.z;
    gemm_body<float>(A + z * Khalf, B + z * Khalf, C + (long)z * LQ * CDIM,
                     lda, ldb, ldc, Khalf, blockIdx.x, blockIdx.x, blockIdx.y);
}

// ---------------------------------------------------------------------------
// Fused attention tile kernel (max-free softmax, log2-domain scores).
// v5 = v1 structure (best measured: 94.7us) with ONE change: P-slab stride
// 72 -> 76 halves (stride 76 measured 0 bank conflicts in v2-v4; stride 72
// measured 1.05M). No XCD swizzle (every swizzled variant was slower).
// Grid (16 q-tiles, 32 = head*2 + kc). Block = 4 waves, 128 q-rows.
// ---------------------------------------------------------------------------
__global__ __launch_bounds__(256, 2) void attn_tile(
    const __half* __restrict__ Qf,  // [2048][2048] normed+roped, log2-scaled
    const __half* __restrict__ Kf,  // kvf [4096][4096]; K in cols 0..2047
    const __half* __restrict__ Vt,  // [2048][4096]  Vt[h*128+d][key]
    float* __restrict__ Opart,      // [2][2048][2048]
    float* __restrict__ lsum)       // [16][2048]
{
    __shared__ __align__(16) __half lK[64 * 128];   // 16 KB
    __shared__ __align__(16) __half lV[128 * 64];   // 16 KB
    __shared__ __align__(16) __half pL[4 * 2 * 16 * 76];  // 19 KB

    const int tid  = threadIdx.x;
    const int lane = tid & 63;
    const int wave = tid >> 6;
    const int l15  = lane & 15;
    const int quad = lane >> 4;
    const int h  = blockIdx.y >> 1;
    const int kc = blockIdx.y & 1;
    const int q0 = blockIdx.x * 128 + wave * 32;   // this wave's 32 q-rows

    // Q A-fragments: A[m=l15][k=ks*32+quad*8+j]
    f16x8 aq[2][4];
#pragma unroll
    for (int mt = 0; mt < 2; ++mt)
#pragma unroll
        for (int ks = 0; ks < 4; ++ks)
            aq[mt][ks] = *(const f16x8*)&Qf[(long)(q0 + mt * 16 + l15) * CDIM +
                                            h * HDIM + ks * 32 + quad * 8];

    // staging pointers. LDS[r][g] = global[r][g ^ (r & mask)] (XOR swizzle in
    // the SOURCE address; LDS dest is wave-uniform base + lane*16).
    const int rK = tid >> 4;          // K row 0..15 (+16/issue)
    const int gK = tid & 15;          // 16 groups of 8 halves
    const __half* srcK = Kf + (long)(kc * 2048 + rK) * 4096 + h * HDIM +
                         ((gK ^ (rK & 15)) << 3);
    const int rV = tid >> 3;          // V row (d) 0..31 (+32/issue)
    const int gV = tid & 7;           // 8 groups of 8 halves
    const __half* srcV = Vt + (long)(h * HDIM + rV) * (long)LKEY + kc * 2048 +
                         ((gV ^ (rV & 7)) << 3);
    __half* dstK = lK + tid * 8;
    __half* dstV = lV + tid * 8;

    f32x4 accO[2][8] = {};
    f32x4 l_acc[2] = {};

    for (int st = 0; st < 32; ++st) {
#pragma unroll
        for (int i = 0; i < 4; ++i) {
            GLOAD_LDS16(srcK + (long)(st * 64 + i * 16) * 4096, dstK + i * 2048);
            GLOAD_LDS16(srcV + (long)i * 32 * LKEY + st * 64, dstV + i * 2048);
        }
        __syncthreads();
        // ---- QK^T (acc init -10 folds the exp2 bias) ----
        f32x4 s[2][4];
#pragma unroll
        for (int mt = 0; mt < 2; ++mt)
#pragma unroll
            for (int nt = 0; nt < 4; ++nt)
                s[mt][nt] = (f32x4){-10.f, -10.f, -10.f, -10.f};
#pragma unroll
        for (int nt = 0; nt < 4; ++nt) {
            const int n = nt * 16 + l15;
#pragma unroll
            for (int ks = 0; ks < 4; ++ks) {
                const f16x8 kf = *(const f16x8*)
                    &lK[n * 128 + (((ks * 4 + quad) ^ (n & 15)) << 3)];
                s[0][nt] = MFMA16(aq[0][ks], kf, s[0][nt]);
                s[1][nt] = MFMA16(aq[1][ks], kf, s[1][nt]);
            }
        }
        // ---- P = exp2(s), accumulate l, stage P (per-wave slab) ----
#pragma unroll
        for (int mt = 0; mt < 2; ++mt)
#pragma unroll
            for (int nt = 0; nt < 4; ++nt)
#pragma unroll
                for (int r2 = 0; r2 < 4; ++r2) {
                    const float p = __builtin_amdgcn_exp2f(s[mt][nt][r2]);
                    l_acc[mt][r2] += p;
                    pL[((wave * 2 + mt) * 16 + quad * 4 + r2) * 76 +
                       nt * 16 + l15] = __float2half(p);
                }
        // ---- PV ----
        f16x8 ap[2][2];
#pragma unroll
        for (int mt = 0; mt < 2; ++mt) {
            ap[mt][0] = *(const f16x8*)&pL[((wave * 2 + mt) * 16 + l15) * 76 + quad * 8];
            ap[mt][1] = *(const f16x8*)&pL[((wave * 2 + mt) * 16 + l15) * 76 + 32 + quad * 8];
        }
#pragma unroll
        for (int nt2 = 0; nt2 < 8; ++nt2) {
            const int n2 = nt2 * 16 + l15;
            const f16x8 v0 = *(const f16x8*)&lV[n2 * 64 + ((quad ^ (n2 & 7)) << 3)];
            const f16x8 v1 = *(const f16x8*)&lV[n2 * 64 + (((4 + quad) ^ (n2 & 7)) << 3)];
            accO[0][nt2] = MFMA16(ap[0][0], v0, accO[0][nt2]);
            accO[0][nt2] = MFMA16(ap[0][1], v1, accO[0][nt2]);
            accO[1][nt2] = MFMA16(ap[1][0], v0, accO[1][nt2]);
            accO[1][nt2] = MFMA16(ap[1][1], v1, accO[1][nt2]);
        }
        __syncthreads();
    }

    // ---- l: reduce across the 16 l15 lanes, publish via atomics ----
#pragma unroll
    for (int mt = 0; mt < 2; ++mt)
#pragma unroll
        for (int r2 = 0; r2 < 4; ++r2) {
            float v = l_acc[mt][r2];
            v += __shfl_xor(v, 1);
            v += __shfl_xor(v, 2);
            v += __shfl_xor(v, 4);
            v += __shfl_xor(v, 8);
            if (l15 == 0)
                atomicAdd(&lsum[h * LQ + q0 + mt * 16 + quad * 4 + r2], v);
        }
    // ---- O partial (fp32) ----
    float* Cp = Opart + (long)kc * LQ * CDIM + h * HDIM;
#pragma unroll
    for (int mt = 0; mt < 2; ++mt)
#pragma unroll
        for (int nt2 = 0; nt2 < 8; ++nt2)
#pragma unroll
            for (int rx = 0; rx < 4; ++rx)
                Cp[(long)(q0 + mt * 16 + quad * 4 + rx) * CDIM + nt2 * 16 + l15] =
                    accO[mt][nt2][rx];
}

// ---------------------------------------------------------------------------
// merge: a2[q][c] = (Op0+Op1)[q][c] / lsum[c>>7][q]   (fp16 out)
// ---------------------------------------------------------------------------
__global__ __launch_bounds__(256) void merge_o(
    const float* __restrict__ Op, const float* __restrict__ lsum,
    __half* __restrict__ a2)
{
    const int row = blockIdx.x;
    const int c0  = threadIdx.x * 8;
    const float inv = 1.0f / lsum[(c0 >> 7) * LQ + row];
    const float* p0 = Op + (long)row * CDIM + c0;
    const float* p1 = p0 + (long)LQ * CDIM;
    union { f16x8 v; _Float16 e[8]; } o;
#pragma unroll
    for (int j = 0; j < 8; ++j)
        o.e[j] = (_Float16)((p0[j] + p1[j]) * inv);
    *(f16x8*)&a2[(long)row * 4096 + c0] = o.v;
}

// ---------------------------------------------------------------------------
// In-place per-(row,head) rmsnorm + depth-rope on fp16 data (D=128).
// ---------------------------------------------------------------------------
__global__ __launch_bounds__(256) void norm_rope(
    __half* __restrict__ X, const float* __restrict__ w,
    int stride, int nrows, int kmode, float oscale)
{
    const int gid  = blockIdx.x * 4 + (threadIdx.x >> 6);
    const int lane = threadIdx.x & 63;
    const int row  = gid >> 4;
    const int h    = gid & 15;
    if (row >= nrows) return;
    __half* p = X + (long)row * stride + h * HDIM;
    float x1 = __half2float(p[lane]);
    float x2 = __half2float(p[lane + 64]);
    float ss = x1 * x1 + x2 * x2;
#pragma unroll
    for (int off = 1; off < 64; off <<= 1) ss += __shfl_xor(ss, off);
    const float rn = rsqrtf(ss * (1.0f / 128.0f) + 1e-6f);
    x1 *= rn * w[lane];
    x2 *= rn * w[lane + 64];
    const int depth = kmode ? (row < LQ ? 0 : 1) : 2;
    const float freq = exp2f(-(float)lane * 0.20762050593045702f);
    const float ang = (float)depth * freq;
    float sn, cs;
    __sincosf(ang, &sn, &cs);
    p[lane]      = __float2half((x1 * cs - x2 * sn) * oscale);
    p[lane + 64] = __float2half((x1 * sn + x2 * cs) * oscale);
}

// ---------------------------------------------------------------------------
// helpers
// ---------------------------------------------------------------------------
// All six fp32->fp16 input casts in ONE launch (was 6 launches).
// 6 chunks of 4M elements; 4 elements/thread.
__global__ __launch_bounds__(256) void cast_all(
    const float* __restrict__ h2, const float* __restrict__ h0,
    const float* __restrict__ h1, const float* __restrict__ Wq,
    const float* __restrict__ Wk, const float* __restrict__ Wv,
    __half* __restrict__ xq, __half* __restrict__ xkv,
    __half* __restrict__ wqh, __half* __restrict__ wkv)
{
    const long i = ((long)blockIdx.x * 256 + threadIdx.x) << 2;
    const int chunk = (int)(i >> 22);
    const long off = i & 4194303;
    const float* s; __half* d;
    switch (chunk) {
        case 0:  s = h2; d = xq;            break;
        case 1:  s = h0; d = xkv;           break;
        case 2:  s = h1; d = xkv + 4194304; break;
        case 3:  s = Wq; d = wqh;           break;
        case 4:  s = Wk; d = wkv;           break;
        default: s = Wv; d = wkv + 4194304; break;
    }
    const float4 v = *(const float4*)&s[off];
    f16x4 o;
    o[0] = (_Float16)v.x; o[1] = (_Float16)v.y;
    o[2] = (_Float16)v.z; o[3] = (_Float16)v.w;
    *(f16x4*)&d[off] = o;
}

__global__ void cast_wo(const float* __restrict__ in, __half* __restrict__ out) {
    const int idx = blockIdx.x * 256 + threadIdx.x;
    const int o = idx >> 11, c = idx & 2047;
    out[((long)o << 12) + c] = __float2half(in[idx]);
}

template <typename InT>
__global__ __launch_bounds__(256) void transpose_h(
    const InT* __restrict__ in, long inStride, long inOff,
    __half* __restrict__ out, long outStride, long outOff)
{
    __shared__ float t[64][65];
    const long r0 = (long)blockIdx.x * 64;
    const long c0 = (long)blockIdx.y * 64;
    const int tj = threadIdx.x & 63;
    const int ti = threadIdx.x >> 6;
#pragma unroll
    for (int it = 0; it < 16; ++it) {
        const int i = it * 4 + ti;
        t[i][tj] = toF(in[(r0 + i) * inStride + inOff + c0 + tj]);
    }
    __syncthreads();
#pragma unroll
    for (int it = 0; it < 16; ++it) {
        const int i = it * 4 + ti;
        out[(c0 + i) * outStride + outOff + r0 + tj] = __float2half(t[tj][i]);
    }
}

// 4 elements/thread, HW sin (error ~1e-6 rel << fp16 rounding).
__global__ __launch_bounds__(256) void sin_feat(
    const float* __restrict__ sw1, const float* __restrict__ sb1,
    __half* __restrict__ a2)
{
    const int idx = (blockIdx.x * 256 + threadIdx.x) << 2;
    const int l = idx >> 11, c = idx & 2047;
    const float coord = -1.0f + (2.0f / 2047.0f) * (float)l;
    const float4 w = *(const float4*)&sw1[c];
    const float4 b = *(const float4*)&sb1[c];
    f16x4 o;
    o[0] = (_Float16)__sinf(30.0f * (coord * w.x + b.x));
    o[1] = (_Float16)__sinf(30.0f * (coord * w.y + b.y));
    o[2] = (_Float16)__sinf(30.0f * (coord * w.z + b.z));
    o[3] = (_Float16)__sinf(30.0f * (coord * w.w + b.w));
    *(f16x4*)&a2[((long)l << 12) + 2048 + c] = o;
}

__global__ __launch_bounds__(256) void final_norm(
    const float* __restrict__ out2, const float* __restrict__ x,
    const float* __restrict__ sb2, const float* __restrict__ on_w,
    float* __restrict__ y)
{
    const int row = blockIdx.x;
    const float* o0 = out2 + (long)row * CDIM;
    const float* o1 = o0 + (long)LQ * CDIM;   // split-K partial #2
    float v[8];
    float ss = 0.f;
#pragma unroll
    for (int i = 0; i < 8; ++i) {
        const int c = threadIdx.x + i * 256;
        const float t = o0[c] + o1[c] + sb2[c];
        v[i] = t;
        ss += t * t;
    }
#pragma unroll
    for (int off = 1; off < 64; off <<= 1) ss += __shfl_xor(ss, off);
    __shared__ float red[4];
    const int lane = threadIdx.x & 63, wv = threadIdx.x >> 6;
    if (lane == 0) red[wv] = ss;
    __syncthreads();
    const float tot = red[0] + red[1] + red[2] + red[3];
    const float rn = rsqrtf(tot * (1.0f / 2048.0f) + 1e-6f);
#pragma unroll
    for (int i = 0; i < 8; ++i) {
        const int c = threadIdx.x + i * 256;
        y[(long)row * CDIM + c] = x[(long)row * CDIM + c] + v[i] * rn * on_w[c];
    }
}

// ---------------------------------------------------------------------------
extern "C" void kernel_launch(void* const* d_in, const int* in_sizes, int n_in,
                              void* d_out, int out_size, void* d_ws, size_t ws_size,
                              hipStream_t stream) {
    const float* x    = (const float*)d_in[0];
    const float* h0   = (const float*)d_in[1];
    const float* h1   = (const float*)d_in[2];
    const float* h2   = (const float*)d_in[3];
    const float* Wq   = (const float*)d_in[4];
    const float* Wk   = (const float*)d_in[5];
    const float* Wv   = (const float*)d_in[6];
    const float* Wo   = (const float*)d_in[7];
    const float* qn_w = (const float*)d_in[8];
    const float* kn_w = (const float*)d_in[9];
    const float* on_w = (const float*)d_in[10];
    const float* sw1  = (const float*)d_in[11];
    const float* sb1  = (const float*)d_in[12];
    const float* sw2  = (const float*)d_in[13];
    const float* sb2  = (const float*)d_in[14];
    float* y = (float*)d_out;

    const size_t MB = 1ull << 20;
    char* w = (char*)d_ws;
    __half* xq  = (__half*)(w);             //  8 MB  h2 fp16   [xq;xkv] contiguous
    __half* xkv = (__half*)(w + 8 * MB);    // 16 MB  [h0;h1] fp16
    __half* wqh = (__half*)(w + 24 * MB);   //  8 MB  Wq fp16
    __half* wkv = (__half*)(w + 32 * MB);   // 16 MB  [Wk;Wv] fp16
    __half* qf  = (__half*)(w + 48 * MB);   //  8 MB  Q proj -> normed q
    __half* kvf = (__half*)(w + 56 * MB);   // 32 MB  [K|V] proj (4096x4096)
    __half* vT  = (__half*)(w + 88 * MB);   // 16 MB  V transposed (2048x4096)
    __half* a2  = (__half*)(w + 104 * MB);  // 16 MB  [attn_out | sin_feat]
    __half* b2  = (__half*)(w + 120 * MB);  // 16 MB  [Wo | sw2^T]
    float* Opart = (float*)(w);             // 32 MB  overlays xq/xkv/wqh (dead)
    float* lsum  = (float*)(w + 32 * MB);   // 128 KB overlays wkv (dead)
    float* out2  = (float*)(w + 56 * MB);   // 32 MB  [2] split-K partials,
                                            //        overlays kvf (dead after attn)
    (void)in_sizes; (void)n_in; (void)out_size; (void)ws_size;

    const int n4 = 2048 * 2048;
    cast_all<<<24576, 256, 0, stream>>>(h2, h0, h1, Wq, Wk, Wv, xq, xkv, wqh, wkv);
    cast_wo<<<n4 / 256, 256, 0, stream>>>(Wo, b2);
    transpose_h<float><<<dim3(32, 32), 256, 0, stream>>>(sw2, 2048, 0, b2, 4096, 2048);
    sin_feat<<<4096, 256, 0, stream>>>(sw1, sb1, a2);

    gemm_qkv<<<1280, 256, 0, stream>>>(xq, wqh, wkv, qf, kvf);

    // q pre-scale = log2(e)/sqrt(D): scores arrive in log2 domain for exp2
    norm_rope<<<8192, 256, 0, stream>>>(qf, qn_w, 2048, 2048, 0, 0.12751743f);
    norm_rope<<<16384, 256, 0, stream>>>(kvf, kn_w, 4096, 4096, 1, 1.0f);
    transpose_h<__half><<<dim3(64, 32), 256, 0, stream>>>(kvf, 4096, 2048, vT, 4096, 0);

    (void)hipMemsetAsync(lsum, 0, NHEAD * LQ * sizeof(float), stream);
    attn_tile<<<dim3(16, 32), 256, 0, stream>>>(qf, kvf, vT, Opart, lsum);
    merge_o<<<2048, 256, 0, stream>>>(Opart, lsum, a2);

    gemm_sk<<<dim3(16, 16, 2), 256, 0, stream>>>(a2, b2, out2, 4096, 4096, 2048, 2048);
    final_norm<<<2048, 256, 0, stream>>>(out2, x, sb2, on_w, y);
}